// Round 8
// baseline (170.711 us; speedup 1.0000x reference)
//
#include <hip/hip_runtime.h>
#include <hip/hip_bf16.h>

// Problem constants
#define BSZ 4
#define CH 64
#define IH 128
#define IW 128
#define PN 63          // number of gaussians
#define TLS 32         // 32x32 outputs per block
#define TLH 36         // extended region for 5x5 halo
#define XSD 40         // staging with halo-of-halo
#define NT 64          // 4 images * 4*4 tiles
#define CG 4           // channels per group
#define NG 16          // channel groups
#define NPOS 324       // 18*18 2x2-position blocks over 36x36
#define NPIX (BSZ*IH*IW)   // 65536
// Spline table: quadratic per-interval fit of act(v) on [-355,355], h=5
#define TBN 142
#define TBH 5.0f
#define TBLO (-355.0f)

// ---------------------------------------------------------------------------
// kT: build per-channel quadratic spline tables of the gaussian-mixture
// activation. Channel 0..63 = w0 rows; channel 64 = w1.  Coeffs (A,B,C):
// f(t) = A + B t + C t^2 on t in [0,1) per interval; f' exact deriv of fit.
// ---------------------------------------------------------------------------
__global__ __launch_bounds__(160) void kT(const float* __restrict__ w0,
                                          const float* __restrict__ w1,
                                          float4* __restrict__ tab) {
    __shared__ float wsh[PN];
    const int ch = blockIdx.x;
    const float* w = (ch < CH) ? (w0 + (size_t)ch * PN) : w1;
    if (threadIdx.x < PN) wsh[threadIdx.x] = w[threadIdx.x];
    __syncthreads();
    const int i = threadIdx.x;
    if (i >= TBN) return;
    const float x0 = TBLO + TBH * i, xm = x0 + 0.5f * TBH, x1 = x0 + TBH;
    float f0 = 0.f, fm = 0.f, f1 = 0.f;
    for (int p = 0; p < PN; ++p) {
        const float mu = -310.0f + 10.0f * (float)p, wv = wsh[p];
        const float d0 = x0 - mu, dm = xm - mu, d1 = x1 - mu;
        f0 = __fmaf_rn(wv, __expf(d0 * d0 * -0.005f), f0);
        fm = __fmaf_rn(wv, __expf(dm * dm * -0.005f), fm);
        f1 = __fmaf_rn(wv, __expf(d1 * d1 * -0.005f), f1);
    }
    tab[(size_t)ch * TBN + i] =
        make_float4(f0, -3.f * f0 + 4.f * fm - f1, 2.f * f0 - 4.f * fm + 2.f * f1, 0.f);
}

// value+gradient from spline (tb = LDS table for this channel)
__device__ __forceinline__ void act_tab(float v, const float4* __restrict__ tb,
                                        float& av, float& ag) {
    float u = __fmaf_rn(v, 1.0f / TBH, -TBLO / TBH);
    u = fminf(fmaxf(u, 0.0f), (float)TBN);
    const int idx = min((int)u, TBN - 1);
    const float t = u - (float)idx;
    const float4 c = tb[idx];
    av = __fmaf_rn(t, __fmaf_rn(t, c.z, c.y), c.x);
    ag = __fmaf_rn(t + t, c.z, c.y) * (1.0f / TBH);
}

__device__ __forceinline__ float act_tab_v(float v, const float4* __restrict__ tb) {
    float u = __fmaf_rn(v, 1.0f / TBH, -TBLO / TBH);
    u = fminf(fmaxf(u, 0.0f), (float)TBN);
    const int idx = min((int)u, TBN - 1);
    const float t = u - (float)idx;
    const float4 c = tb[idx];
    return __fmaf_rn(t, __fmaf_rn(t, c.z, c.y), c.x);
}

// ---------------------------------------------------------------------------
// kAB: per block (tile, 4-channel group):
//   phase 1: a0/g0 on ext 36x36 via 2x2 register tiles (6x6 window serves
//            4 outputs x 25 taps x 4 channels); act via spline table.
//            a0 -> LDS, g0 -> global bf16 (interior only).
//   phase 2: partial c1 = sum_cc f1_cc (*) a0_cc -> c1p plane (NO atomics).
// ---------------------------------------------------------------------------
__global__ __launch_bounds__(256) void kAB(const float* __restrict__ x,
                                           const float* __restrict__ f0,
                                           const float* __restrict__ b0,
                                           const float* __restrict__ f1,
                                           const float4* __restrict__ tab,
                                           float* __restrict__ c1p,
                                           __hip_bfloat16* __restrict__ g0out) {
    __shared__ float xs[XSD * XSD];          // 6.4 KB
    __shared__ float a0s[CG][TLH * TLH];     // 20.7 KB
    __shared__ float4 tbs[CG][TBN];          // 9.1 KB

    const int tile = blockIdx.x;
    const int cgi  = blockIdx.y;
    const int cg   = cgi * CG;
    const int b    = tile >> 4;
    const int t    = tile & 15;
    const int h0   = (t >> 2) * TLS;
    const int w0p  = (t & 3) * TLS;
    const int tid  = threadIdx.x;

    for (int i = tid; i < XSD * XSD; i += 256) {
        int iy = i / XSD, ix = i - iy * XSD;
        int gy = min(max(h0 + iy - 4, 0), IH - 1);
        int gx = min(max(w0p + ix - 4, 0), IW - 1);
        xs[i] = x[((size_t)b * IH + gy) * IW + gx] * 255.0f;
    }
    for (int i = tid; i < CG * TBN; i += 256) {
        int cc = i / TBN, k = i - cc * TBN;
        tbs[cc][k] = tab[(size_t)(cg + cc) * TBN + k];
    }
    __syncthreads();

    // phase 1: conv0 + act on 2x2 position blocks
    for (int p = tid; p < NPOS; p += 256) {
        const int pyb = p / 18, pxb = p - pyb * 18;
        const int py = 2 * pyb, px = 2 * pxb;
        const int gy0 = h0 + py - 2, gx0 = w0p + px - 2;
        const int gy1 = gy0 + 1,     gx1 = gx0 + 1;
        const int gyc0 = min(max(gy0, 0), IH - 1), gyc1 = min(max(gy1, 0), IH - 1);
        const int gxc0 = min(max(gx0, 0), IW - 1), gxc1 = min(max(gx1, 0), IW - 1);
        const int cy0 = gyc0 - h0 + 4, cx0 = gxc0 - w0p + 4;
        const int ry1 = (gyc1 - h0 + 4) - cy0;     // 0 or 1
        const int rx1 = (gxc1 - w0p + 4) - cx0;    // 0 or 1
        const bool iny0 = (gy0 == gyc0), iny1 = (gy1 == gyc1);
        const bool inx0 = (gx0 == gxc0), inx1 = (gx1 == gxc1);

        float win[6][6];
#pragma unroll
        for (int r = 0; r < 6; ++r)
#pragma unroll
            for (int c = 0; c < 6; ++c)
                win[r][c] = xs[(cy0 - 2 + r) * XSD + cx0 - 2 + c];

        for (int cc = 0; cc < CG; ++cc) {
            const int c = cg + cc;
            const float bias = b0[c];
            float a00 = bias, a01 = bias, a10 = bias, a11 = bias;
#pragma unroll
            for (int u = 0; u < 5; ++u)
#pragma unroll
                for (int v = 0; v < 5; ++v) {
                    const float kv = f0[(size_t)c * 25 + u * 5 + v];
                    a00 = __fmaf_rn(win[u][v],             kv, a00);
                    a01 = __fmaf_rn(win[u][rx1 + v],       kv, a01);
                    a10 = __fmaf_rn(win[ry1 + u][v],       kv, a10);
                    a11 = __fmaf_rn(win[ry1 + u][rx1 + v], kv, a11);
                }
            float av, ag;
            const size_t gb = ((size_t)b * CH + c) * (IH * IW);
            act_tab(a00, tbs[cc], av, ag);
            a0s[cc][py * TLH + px] = av;
            if (iny0 && inx0) g0out[gb + gy0 * IW + gx0] = __float2bfloat16(ag);
            act_tab(a01, tbs[cc], av, ag);
            a0s[cc][py * TLH + px + 1] = av;
            if (iny0 && inx1) g0out[gb + gy0 * IW + gx1] = __float2bfloat16(ag);
            act_tab(a10, tbs[cc], av, ag);
            a0s[cc][(py + 1) * TLH + px] = av;
            if (iny1 && inx0) g0out[gb + gy1 * IW + gx0] = __float2bfloat16(ag);
            act_tab(a11, tbs[cc], av, ag);
            a0s[cc][(py + 1) * TLH + px + 1] = av;
            if (iny1 && inx1) g0out[gb + gy1 * IW + gx1] = __float2bfloat16(ag);
        }
    }
    __syncthreads();

    // phase 2: partial c1, 2x2/thread -> c1p plane
    const int lx = tid & 15, ly = tid >> 4;
    const int r0 = 2 * ly, c0 = 2 * lx;
    float a00 = 0.f, a01 = 0.f, a10 = 0.f, a11 = 0.f;

#pragma unroll
    for (int cc = 0; cc < CG; ++cc) {
        float win[6][6];
#pragma unroll
        for (int r = 0; r < 6; ++r) {
            const float2* rp = (const float2*)&a0s[cc][(r0 + r) * TLH + c0];
            float2 p0 = rp[0], p1 = rp[1], p2 = rp[2];
            win[r][0] = p0.x; win[r][1] = p0.y; win[r][2] = p1.x;
            win[r][3] = p1.y; win[r][4] = p2.x; win[r][5] = p2.y;
        }
#pragma unroll
        for (int u = 0; u < 5; ++u)
#pragma unroll
            for (int v = 0; v < 5; ++v) {
                const float kv = f1[(size_t)(cg + cc) * 25 + u * 5 + v];
                a00 = __fmaf_rn(win[u][v],         kv, a00);
                a01 = __fmaf_rn(win[u][v + 1],     kv, a01);
                a10 = __fmaf_rn(win[u + 1][v],     kv, a10);
                a11 = __fmaf_rn(win[u + 1][v + 1], kv, a11);
            }
    }

    const size_t base = (size_t)cgi * NPIX + ((size_t)b * IH + h0 + r0) * IW + w0p + c0;
    *(float2*)&c1p[base]      = make_float2(a00, a01);
    *(float2*)&c1p[base + IW] = make_float2(a10, a11);
}

// ---------------------------------------------------------------------------
// kB2: a1 = act_spline(b1 + sum of 16 c1p partials)  (channel-64 table)
// ---------------------------------------------------------------------------
__global__ __launch_bounds__(256) void kB2(const float* __restrict__ c1p,
                                           const float* __restrict__ b1,
                                           const float4* __restrict__ tab,
                                           float* __restrict__ a1) {
    __shared__ float4 tbs[TBN];
    const int tid = threadIdx.x;
    if (tid < TBN) tbs[tid] = tab[(size_t)CH * TBN + tid];
    __syncthreads();

    const int pid = blockIdx.x * 256 + tid;
    float vv = b1[0];
#pragma unroll
    for (int g = 0; g < NG; ++g) vv += c1p[(size_t)g * NPIX + pid];
    a1[pid] = act_tab_v(vv, tbs);
}

// ---------------------------------------------------------------------------
// kCD: per block (tile, 4-channel group):
//   phase 1: dbuf_cc = conv_t5(a1) * g0 on ext 36x36 via 2x2 register tiles
//   phase 2: partial d3 = sum_cc f0_cc full-corr dbuf_cc -> d3p plane.
// ---------------------------------------------------------------------------
__global__ __launch_bounds__(256) void kCD(const float* __restrict__ a1,
                                           const float* __restrict__ f1,
                                           const float* __restrict__ f0,
                                           const __hip_bfloat16* __restrict__ g0,
                                           float* __restrict__ d3p) {
    __shared__ float a1s[XSD * XSD];         // 6.4 KB
    __shared__ float dbs[CG][TLH * TLH];     // 20.7 KB

    const int tile = blockIdx.x;
    const int cgi  = blockIdx.y;
    const int cg   = cgi * CG;
    const int b    = tile >> 4;
    const int t    = tile & 15;
    const int h0   = (t >> 2) * TLS;
    const int w0p  = (t & 3) * TLS;
    const int tid  = threadIdx.x;

    for (int p = tid; p < XSD * XSD; p += 256) {
        int iy = p / XSD, ix = p - iy * XSD;
        int gy = h0 + iy - 4, gx = w0p + ix - 4;
        float v = 0.0f;
        if ((unsigned)gy < IH && (unsigned)gx < IW)
            v = a1[((size_t)b * IH + gy) * IW + gx];
        a1s[p] = v;
    }
    __syncthreads();

    // phase 1: conv_t * g0 on 2x2 position blocks
    for (int p = tid; p < NPOS; p += 256) {
        const int pyb = p / 18, pxb = p - pyb * 18;
        const int py = 2 * pyb, px = 2 * pxb;
        const int gy0 = h0 + py - 2, gx0 = w0p + px - 2;
        const bool iny0 = (unsigned)gy0 < IH, iny1 = (unsigned)(gy0 + 1) < IH;
        const bool inx0 = (unsigned)gx0 < IW, inx1 = (unsigned)(gx0 + 1) < IW;

        float win[6][6];
#pragma unroll
        for (int r = 0; r < 6; ++r) {
            const float2* rp = (const float2*)&a1s[(py + r) * XSD + px];
            float2 p0 = rp[0], p1 = rp[1], p2 = rp[2];
            win[r][0] = p0.x; win[r][1] = p0.y; win[r][2] = p1.x;
            win[r][3] = p1.y; win[r][4] = p2.x; win[r][5] = p2.y;
        }

        for (int cc = 0; cc < CG; ++cc) {
            const int c = cg + cc;
            float d00 = 0.f, d01 = 0.f, d10 = 0.f, d11 = 0.f;
#pragma unroll
            for (int u = 0; u < 5; ++u)
#pragma unroll
                for (int v = 0; v < 5; ++v) {
                    const float kv = f1[(size_t)c * 25 + u * 5 + v];
                    d00 = __fmaf_rn(win[4 - u][4 - v], kv, d00);
                    d01 = __fmaf_rn(win[4 - u][5 - v], kv, d01);
                    d10 = __fmaf_rn(win[5 - u][4 - v], kv, d10);
                    d11 = __fmaf_rn(win[5 - u][5 - v], kv, d11);
                }
            const size_t gb = ((size_t)b * CH + c) * (IH * IW);
            float o00 = 0.f, o01 = 0.f, o10 = 0.f, o11 = 0.f;
            if (iny0 && inx0) o00 = d00 * __bfloat162float(g0[gb + gy0 * IW + gx0]);
            if (iny0 && inx1) o01 = d01 * __bfloat162float(g0[gb + gy0 * IW + gx0 + 1]);
            if (iny1 && inx0) o10 = d10 * __bfloat162float(g0[gb + (gy0 + 1) * IW + gx0]);
            if (iny1 && inx1) o11 = d11 * __bfloat162float(g0[gb + (gy0 + 1) * IW + gx0 + 1]);
            dbs[cc][py * TLH + px]           = o00;
            dbs[cc][py * TLH + px + 1]       = o01;
            dbs[cc][(py + 1) * TLH + px]     = o10;
            dbs[cc][(py + 1) * TLH + px + 1] = o11;
        }
    }
    __syncthreads();

    // phase 2: partial d3, 2x2/thread -> d3p plane
    const int lx = tid & 15, ly = tid >> 4;
    const int r0 = 2 * ly, c0 = 2 * lx;
    float a00 = 0.f, a01 = 0.f, a10 = 0.f, a11 = 0.f;

#pragma unroll
    for (int cc = 0; cc < CG; ++cc) {
        float win[6][6];
#pragma unroll
        for (int r = 0; r < 6; ++r) {
            const float2* rp = (const float2*)&dbs[cc][(r0 + r) * TLH + c0];
            float2 p0 = rp[0], p1 = rp[1], p2 = rp[2];
            win[r][0] = p0.x; win[r][1] = p0.y; win[r][2] = p1.x;
            win[r][3] = p1.y; win[r][4] = p2.x; win[r][5] = p2.y;
        }
#pragma unroll
        for (int u = 0; u < 5; ++u)
#pragma unroll
            for (int v = 0; v < 5; ++v) {
                const float kv = f0[(size_t)(cg + cc) * 25 + u * 5 + v];
                a00 = __fmaf_rn(win[4 - u][4 - v], kv, a00);
                a01 = __fmaf_rn(win[4 - u][5 - v], kv, a01);
                a10 = __fmaf_rn(win[5 - u][4 - v], kv, a10);
                a11 = __fmaf_rn(win[5 - u][5 - v], kv, a11);
            }
    }

    const size_t base = (size_t)cgi * NPIX + ((size_t)b * IH + h0 + r0) * IW + w0p + c0;
    *(float2*)&d3p[base]      = make_float2(a00, a01);
    *(float2*)&d3p[base + IW] = make_float2(a10, a11);
}

// ---------------------------------------------------------------------------
// kE: out = x - (sum of 16 d3 partials)/255 - exp(lam)*(x-y)
// ---------------------------------------------------------------------------
__global__ __launch_bounds__(256) void kE(const float* __restrict__ d3p,
                                          const float* __restrict__ x,
                                          const float* __restrict__ y,
                                          const float* __restrict__ lam_param,
                                          float* __restrict__ out) {
    const int pid = blockIdx.x * 256 + threadIdx.x;
    float d3 = 0.0f;
#pragma unroll
    for (int g = 0; g < NG; ++g) d3 += d3p[(size_t)g * NPIX + pid];
    const float elam = __expf(lam_param[0]);
    const float xv = x[pid], yv = y[pid];
    out[pid] = xv - d3 * (1.0f / 255.0f) - elam * (xv - yv);
}

// ---------------------------------------------------------------------------
extern "C" void kernel_launch(void* const* d_in, const int* in_sizes, int n_in,
                              void* d_out, int out_size, void* d_ws, size_t ws_size,
                              hipStream_t stream) {
    const float* x   = (const float*)d_in[0];
    const float* y   = (const float*)d_in[1];
    // d_in[2] = lam (ignored by reference)
    const float* f0  = (const float*)d_in[3];
    const float* b0  = (const float*)d_in[4];
    const float* f1  = (const float*)d_in[5];
    const float* b1  = (const float*)d_in[6];
    const float* w0  = (const float*)d_in[7];
    const float* w1  = (const float*)d_in[8];
    const float* lam = (const float*)d_in[9];
    float* out = (float*)d_out;

    const size_t nch = (size_t)BSZ * CH * IH * IW;   // 4.19M elements
    __hip_bfloat16* g0 = (__hip_bfloat16*)d_ws;      // 8.4 MB (bf16)
    float4* tab = (float4*)(g0 + nch);               // 65*TBN float4 (148 KB)
    float* c1p  = (float*)(tab + (size_t)(CH + 1) * TBN);  // NG*NPIX (4.2 MB)
    float* a1   = c1p + (size_t)NG * NPIX;           // 0.26 MB
    float* d3p  = a1 + NPIX;                         // NG*NPIX (4.2 MB)

    kT <<<CH + 1, 160, 0, stream>>>(w0, w1, tab);
    kAB<<<dim3(NT, NG), 256, 0, stream>>>(x, f0, b0, f1, tab, c1p, g0);
    kB2<<<NPIX / 256, 256, 0, stream>>>(c1p, b1, tab, a1);
    kCD<<<dim3(NT, NG), 256, 0, stream>>>(a1, f1, f0, g0, d3p);
    kE <<<NPIX / 256, 256, 0, stream>>>(d3p, x, y, lam, out);
}

// Round 9
// 125.227 us; speedup vs baseline: 1.3632x; 1.3632x over previous
//
#include <hip/hip_runtime.h>
#include <hip/hip_bf16.h>

// Problem constants
#define BSZ 4
#define CH 64
#define IH 128
#define IW 128
#define PN 63          // number of gaussians
#define TLS 32         // 32x32 outputs per block
#define TLH 36         // extended region for 5x5 halo
#define XSD 40         // staging with halo-of-halo
#define NT 64          // 4 images * 4*4 tiles
#define CG 4           // channels per group
#define NG 16          // channel groups
#define NPOS 324       // 18*18 2x2-position blocks over 36x36
#define NPIX (BSZ*IH*IW)   // 65536
// Spline table: quadratic per-interval fit of act(v) on [-355,355], h=5
#define TBN 142
#define TBH 5.0f
#define TBLO (-355.0f)

// ---------------------------------------------------------------------------
// kT: build per-channel quadratic spline tables of the gaussian-mixture
// activation. Channel 0..63 = w0 rows; channel 64 = w1.
// ---------------------------------------------------------------------------
__global__ __launch_bounds__(160) void kT(const float* __restrict__ w0,
                                          const float* __restrict__ w1,
                                          float4* __restrict__ tab) {
    __shared__ float wsh[PN];
    const int ch = blockIdx.x;
    const float* w = (ch < CH) ? (w0 + (size_t)ch * PN) : w1;
    if (threadIdx.x < PN) wsh[threadIdx.x] = w[threadIdx.x];
    __syncthreads();
    const int i = threadIdx.x;
    if (i >= TBN) return;
    const float x0 = TBLO + TBH * i, xm = x0 + 0.5f * TBH, x1 = x0 + TBH;
    float f0 = 0.f, fm = 0.f, f1 = 0.f;
    for (int p = 0; p < PN; ++p) {
        const float mu = -310.0f + 10.0f * (float)p, wv = wsh[p];
        const float d0 = x0 - mu, dm = xm - mu, d1 = x1 - mu;
        f0 = __fmaf_rn(wv, __expf(d0 * d0 * -0.005f), f0);
        fm = __fmaf_rn(wv, __expf(dm * dm * -0.005f), fm);
        f1 = __fmaf_rn(wv, __expf(d1 * d1 * -0.005f), f1);
    }
    tab[(size_t)ch * TBN + i] =
        make_float4(f0, -3.f * f0 + 4.f * fm - f1, 2.f * f0 - 4.f * fm + 2.f * f1, 0.f);
}

// value+gradient from spline (tb = LDS table for this channel)
__device__ __forceinline__ void act_tab(float v, const float4* __restrict__ tb,
                                        float& av, float& ag) {
    float u = __fmaf_rn(v, 1.0f / TBH, -TBLO / TBH);
    u = fminf(fmaxf(u, 0.0f), (float)TBN);
    const int idx = min((int)u, TBN - 1);
    const float t = u - (float)idx;
    const float4 c = tb[idx];
    av = __fmaf_rn(t, __fmaf_rn(t, c.z, c.y), c.x);
    ag = __fmaf_rn(t + t, c.z, c.y) * (1.0f / TBH);
}

__device__ __forceinline__ float act_tab_v(float v, const float4* __restrict__ tb) {
    float u = __fmaf_rn(v, 1.0f / TBH, -TBLO / TBH);
    u = fminf(fmaxf(u, 0.0f), (float)TBN);
    const int idx = min((int)u, TBN - 1);
    const float t = u - (float)idx;
    const float4 c = tb[idx];
    return __fmaf_rn(t, __fmaf_rn(t, c.z, c.y), c.x);
}

// ---------------------------------------------------------------------------
// kAB: per block (tile, 4-channel group):
//   phase 1: conv0+act at ALL ext 36x36 positions, 2x2 register tiles with
//            ONLY compile-time register indices (no scratch). Outside-image
//            positions compute garbage (finite).
//   phase 1.5: rep_pad fixup IN LDS: a0s[p] = a0s[clamp(p)] for outside-image
//            positions (runtime LDS addresses are fine).
//   phase 2: partial c1 = sum_cc f1_cc (*) a0_cc -> c1p plane.
//   g0 (bf16) written for the true 32x32 interior only, as bf16x2 pairs.
// ---------------------------------------------------------------------------
__global__ __launch_bounds__(256) void kAB(const float* __restrict__ x,
                                           const float* __restrict__ f0,
                                           const float* __restrict__ b0,
                                           const float* __restrict__ f1,
                                           const float4* __restrict__ tab,
                                           float* __restrict__ c1p,
                                           __hip_bfloat16* __restrict__ g0out) {
    __shared__ float xs[XSD * XSD];          // 6.4 KB
    __shared__ float a0s[CG][TLH * TLH];     // 20.7 KB
    __shared__ float4 tbs[CG][TBN];          // 9.1 KB

    const int tile = blockIdx.x;
    const int cgi  = blockIdx.y;
    const int cg   = cgi * CG;
    const int b    = tile >> 4;
    const int t    = tile & 15;
    const int h0   = (t >> 2) * TLS;
    const int w0p  = (t & 3) * TLS;
    const int tid  = threadIdx.x;

    for (int i = tid; i < XSD * XSD; i += 256) {
        int iy = i / XSD, ix = i - iy * XSD;
        int gy = min(max(h0 + iy - 4, 0), IH - 1);
        int gx = min(max(w0p + ix - 4, 0), IW - 1);
        xs[i] = x[((size_t)b * IH + gy) * IW + gx] * 255.0f;
    }
    for (int i = tid; i < CG * TBN; i += 256) {
        int cc = i / TBN, k = i - cc * TBN;
        tbs[cc][k] = tab[(size_t)(cg + cc) * TBN + k];
    }
    __syncthreads();

    // phase 1: conv0 + act on 2x2 position blocks, all indices constant
    for (int p = tid; p < NPOS; p += 256) {
        const int pyb = p / 18, pxb = p - pyb * 18;
        const int py = 2 * pyb, px = 2 * pxb;
        // window rows py..py+5, cols px..px+5 in xs (center of (py,px) is
        // xs coord (py+2, px+2)); px even -> float2 aligned
        float win[6][6];
#pragma unroll
        for (int r = 0; r < 6; ++r) {
            const float2* rp = (const float2*)&xs[(py + r) * XSD + px];
            float2 p0 = rp[0], p1 = rp[1], p2 = rp[2];
            win[r][0] = p0.x; win[r][1] = p0.y; win[r][2] = p1.x;
            win[r][3] = p1.y; win[r][4] = p2.x; win[r][5] = p2.y;
        }
        // both pixels of the 2x2 pair share interior validity (band [2,33])
        const bool vy = (py >= 2) && (py < 34);
        const bool vx = (px >= 2) && (px < 34);
        const int gy0 = h0 + py - 2, gx0 = w0p + px - 2;

        for (int cc = 0; cc < CG; ++cc) {
            const int c = cg + cc;
            const float bias = b0[c];
            float a00 = bias, a01 = bias, a10 = bias, a11 = bias;
#pragma unroll
            for (int u = 0; u < 5; ++u)
#pragma unroll
                for (int v = 0; v < 5; ++v) {
                    const float kv = f0[(size_t)c * 25 + u * 5 + v];
                    a00 = __fmaf_rn(win[u][v],         kv, a00);
                    a01 = __fmaf_rn(win[u][v + 1],     kv, a01);
                    a10 = __fmaf_rn(win[u + 1][v],     kv, a10);
                    a11 = __fmaf_rn(win[u + 1][v + 1], kv, a11);
                }
            float av0, ag0, av1, ag1, av2, ag2, av3, ag3;
            act_tab(a00, tbs[cc], av0, ag0);
            act_tab(a01, tbs[cc], av1, ag1);
            act_tab(a10, tbs[cc], av2, ag2);
            act_tab(a11, tbs[cc], av3, ag3);
            *(float2*)&a0s[cc][py * TLH + px]       = make_float2(av0, av1);
            *(float2*)&a0s[cc][(py + 1) * TLH + px] = make_float2(av2, av3);
            if (vy && vx) {
                const size_t gb = ((size_t)b * CH + c) * (IH * IW);
                __hip_bfloat162 r0 = {__float2bfloat16(ag0), __float2bfloat16(ag1)};
                __hip_bfloat162 r1 = {__float2bfloat16(ag2), __float2bfloat16(ag3)};
                *(__hip_bfloat162*)&g0out[gb + (size_t)gy0 * IW + gx0]       = r0;
                *(__hip_bfloat162*)&g0out[gb + (size_t)(gy0 + 1) * IW + gx0] = r1;
            }
        }
    }
    __syncthreads();

    // phase 1.5: rep_pad fixup for outside-image ext positions (border tiles)
    if (h0 == 0 || h0 == IH - TLS || w0p == 0 || w0p == IW - TLS) {
        for (int p = tid; p < TLH * TLH; p += 256) {
            const int py = p / TLH, px = p - py * TLH;
            const int gy = h0 + py - 2, gx = w0p + px - 2;
            if ((unsigned)gy >= IH || (unsigned)gx >= IW) {
                const int cpy = min(max(gy, 0), IH - 1) - h0 + 2;
                const int cpx = min(max(gx, 0), IW - 1) - w0p + 2;
                const int src = cpy * TLH + cpx;
#pragma unroll
                for (int cc = 0; cc < CG; ++cc)
                    a0s[cc][p] = a0s[cc][src];
            }
        }
    }
    __syncthreads();

    // phase 2: partial c1, 2x2/thread -> c1p plane
    const int lx = tid & 15, ly = tid >> 4;
    const int r0 = 2 * ly, c0 = 2 * lx;
    float a00 = 0.f, a01 = 0.f, a10 = 0.f, a11 = 0.f;

#pragma unroll
    for (int cc = 0; cc < CG; ++cc) {
        float win[6][6];
#pragma unroll
        for (int r = 0; r < 6; ++r) {
            const float2* rp = (const float2*)&a0s[cc][(r0 + r) * TLH + c0];
            float2 p0 = rp[0], p1 = rp[1], p2 = rp[2];
            win[r][0] = p0.x; win[r][1] = p0.y; win[r][2] = p1.x;
            win[r][3] = p1.y; win[r][4] = p2.x; win[r][5] = p2.y;
        }
#pragma unroll
        for (int u = 0; u < 5; ++u)
#pragma unroll
            for (int v = 0; v < 5; ++v) {
                const float kv = f1[(size_t)(cg + cc) * 25 + u * 5 + v];
                a00 = __fmaf_rn(win[u][v],         kv, a00);
                a01 = __fmaf_rn(win[u][v + 1],     kv, a01);
                a10 = __fmaf_rn(win[u + 1][v],     kv, a10);
                a11 = __fmaf_rn(win[u + 1][v + 1], kv, a11);
            }
    }

    const size_t base = (size_t)cgi * NPIX + ((size_t)b * IH + h0 + r0) * IW + w0p + c0;
    *(float2*)&c1p[base]      = make_float2(a00, a01);
    *(float2*)&c1p[base + IW] = make_float2(a10, a11);
}

// ---------------------------------------------------------------------------
// kB2: a1 = act_spline(b1 + sum of 16 c1p partials)  (channel-64 table)
// ---------------------------------------------------------------------------
__global__ __launch_bounds__(256) void kB2(const float* __restrict__ c1p,
                                           const float* __restrict__ b1,
                                           const float4* __restrict__ tab,
                                           float* __restrict__ a1) {
    __shared__ float4 tbs[TBN];
    const int tid = threadIdx.x;
    if (tid < TBN) tbs[tid] = tab[(size_t)CH * TBN + tid];
    __syncthreads();

    const int pid = blockIdx.x * 256 + tid;
    float vv = b1[0];
#pragma unroll
    for (int g = 0; g < NG; ++g) vv += c1p[(size_t)g * NPIX + pid];
    a1[pid] = act_tab_v(vv, tbs);
}

// ---------------------------------------------------------------------------
// kCD: per block (tile, 4-channel group):
//   phase 1: dbuf_cc = conv_t5(a1) * g0 on ext 36x36 via 2x2 register tiles
//            (all register indices constant: zero-pad, no clamps)
//   phase 2: partial d3 = sum_cc f0_cc full-corr dbuf_cc -> d3p plane.
// ---------------------------------------------------------------------------
__global__ __launch_bounds__(256) void kCD(const float* __restrict__ a1,
                                           const float* __restrict__ f1,
                                           const float* __restrict__ f0,
                                           const __hip_bfloat16* __restrict__ g0,
                                           float* __restrict__ d3p) {
    __shared__ float a1s[XSD * XSD];         // 6.4 KB
    __shared__ float dbs[CG][TLH * TLH];     // 20.7 KB

    const int tile = blockIdx.x;
    const int cgi  = blockIdx.y;
    const int cg   = cgi * CG;
    const int b    = tile >> 4;
    const int t    = tile & 15;
    const int h0   = (t >> 2) * TLS;
    const int w0p  = (t & 3) * TLS;
    const int tid  = threadIdx.x;

    for (int p = tid; p < XSD * XSD; p += 256) {
        int iy = p / XSD, ix = p - iy * XSD;
        int gy = h0 + iy - 4, gx = w0p + ix - 4;
        float v = 0.0f;
        if ((unsigned)gy < IH && (unsigned)gx < IW)
            v = a1[((size_t)b * IH + gy) * IW + gx];
        a1s[p] = v;
    }
    __syncthreads();

    // phase 1: conv_t * g0 on 2x2 position blocks
    for (int p = tid; p < NPOS; p += 256) {
        const int pyb = p / 18, pxb = p - pyb * 18;
        const int py = 2 * pyb, px = 2 * pxb;
        const int gy0 = h0 + py - 2, gx0 = w0p + px - 2;
        const bool iny0 = (unsigned)gy0 < IH, iny1 = (unsigned)(gy0 + 1) < IH;
        const bool inx0 = (unsigned)gx0 < IW, inx1 = (unsigned)(gx0 + 1) < IW;

        float win[6][6];
#pragma unroll
        for (int r = 0; r < 6; ++r) {
            const float2* rp = (const float2*)&a1s[(py + r) * XSD + px];
            float2 p0 = rp[0], p1 = rp[1], p2 = rp[2];
            win[r][0] = p0.x; win[r][1] = p0.y; win[r][2] = p1.x;
            win[r][3] = p1.y; win[r][4] = p2.x; win[r][5] = p2.y;
        }

        for (int cc = 0; cc < CG; ++cc) {
            const int c = cg + cc;
            float d00 = 0.f, d01 = 0.f, d10 = 0.f, d11 = 0.f;
#pragma unroll
            for (int u = 0; u < 5; ++u)
#pragma unroll
                for (int v = 0; v < 5; ++v) {
                    const float kv = f1[(size_t)c * 25 + u * 5 + v];
                    d00 = __fmaf_rn(win[4 - u][4 - v], kv, d00);
                    d01 = __fmaf_rn(win[4 - u][5 - v], kv, d01);
                    d10 = __fmaf_rn(win[5 - u][4 - v], kv, d10);
                    d11 = __fmaf_rn(win[5 - u][5 - v], kv, d11);
                }
            const size_t gb = ((size_t)b * CH + c) * (IH * IW);
            float o00 = 0.f, o01 = 0.f, o10 = 0.f, o11 = 0.f;
            if (iny0 && inx0) o00 = d00 * __bfloat162float(g0[gb + gy0 * IW + gx0]);
            if (iny0 && inx1) o01 = d01 * __bfloat162float(g0[gb + gy0 * IW + gx0 + 1]);
            if (iny1 && inx0) o10 = d10 * __bfloat162float(g0[gb + (gy0 + 1) * IW + gx0]);
            if (iny1 && inx1) o11 = d11 * __bfloat162float(g0[gb + (gy0 + 1) * IW + gx0 + 1]);
            *(float2*)&dbs[cc][py * TLH + px]       = make_float2(o00, o01);
            *(float2*)&dbs[cc][(py + 1) * TLH + px] = make_float2(o10, o11);
        }
    }
    __syncthreads();

    // phase 2: partial d3, 2x2/thread -> d3p plane
    const int lx = tid & 15, ly = tid >> 4;
    const int r0 = 2 * ly, c0 = 2 * lx;
    float a00 = 0.f, a01 = 0.f, a10 = 0.f, a11 = 0.f;

#pragma unroll
    for (int cc = 0; cc < CG; ++cc) {
        float win[6][6];
#pragma unroll
        for (int r = 0; r < 6; ++r) {
            const float2* rp = (const float2*)&dbs[cc][(r0 + r) * TLH + c0];
            float2 p0 = rp[0], p1 = rp[1], p2 = rp[2];
            win[r][0] = p0.x; win[r][1] = p0.y; win[r][2] = p1.x;
            win[r][3] = p1.y; win[r][4] = p2.x; win[r][5] = p2.y;
        }
#pragma unroll
        for (int u = 0; u < 5; ++u)
#pragma unroll
            for (int v = 0; v < 5; ++v) {
                const float kv = f0[(size_t)(cg + cc) * 25 + u * 5 + v];
                a00 = __fmaf_rn(win[4 - u][4 - v], kv, a00);
                a01 = __fmaf_rn(win[4 - u][5 - v], kv, a01);
                a10 = __fmaf_rn(win[5 - u][4 - v], kv, a10);
                a11 = __fmaf_rn(win[5 - u][5 - v], kv, a11);
            }
    }

    const size_t base = (size_t)cgi * NPIX + ((size_t)b * IH + h0 + r0) * IW + w0p + c0;
    *(float2*)&d3p[base]      = make_float2(a00, a01);
    *(float2*)&d3p[base + IW] = make_float2(a10, a11);
}

// ---------------------------------------------------------------------------
// kE: out = x - (sum of 16 d3 partials)/255 - exp(lam)*(x-y)
// ---------------------------------------------------------------------------
__global__ __launch_bounds__(256) void kE(const float* __restrict__ d3p,
                                          const float* __restrict__ x,
                                          const float* __restrict__ y,
                                          const float* __restrict__ lam_param,
                                          float* __restrict__ out) {
    const int pid = blockIdx.x * 256 + threadIdx.x;
    float d3 = 0.0f;
#pragma unroll
    for (int g = 0; g < NG; ++g) d3 += d3p[(size_t)g * NPIX + pid];
    const float elam = __expf(lam_param[0]);
    const float xv = x[pid], yv = y[pid];
    out[pid] = xv - d3 * (1.0f / 255.0f) - elam * (xv - yv);
}

// ---------------------------------------------------------------------------
extern "C" void kernel_launch(void* const* d_in, const int* in_sizes, int n_in,
                              void* d_out, int out_size, void* d_ws, size_t ws_size,
                              hipStream_t stream) {
    const float* x   = (const float*)d_in[0];
    const float* y   = (const float*)d_in[1];
    // d_in[2] = lam (ignored by reference)
    const float* f0  = (const float*)d_in[3];
    const float* b0  = (const float*)d_in[4];
    const float* f1  = (const float*)d_in[5];
    const float* b1  = (const float*)d_in[6];
    const float* w0  = (const float*)d_in[7];
    const float* w1  = (const float*)d_in[8];
    const float* lam = (const float*)d_in[9];
    float* out = (float*)d_out;

    const size_t nch = (size_t)BSZ * CH * IH * IW;   // 4.19M elements
    __hip_bfloat16* g0 = (__hip_bfloat16*)d_ws;      // 8.4 MB (bf16)
    float4* tab = (float4*)(g0 + nch);               // 65*TBN float4 (148 KB)
    float* c1p  = (float*)(tab + (size_t)(CH + 1) * TBN);  // NG*NPIX (4.2 MB)
    float* a1   = c1p + (size_t)NG * NPIX;           // 0.26 MB
    float* d3p  = a1 + NPIX;                         // NG*NPIX (4.2 MB)

    kT <<<CH + 1, 160, 0, stream>>>(w0, w1, tab);
    kAB<<<dim3(NT, NG), 256, 0, stream>>>(x, f0, b0, f1, tab, c1p, g0);
    kB2<<<NPIX / 256, 256, 0, stream>>>(c1p, b1, tab, a1);
    kCD<<<dim3(NT, NG), 256, 0, stream>>>(a1, f1, f0, g0, d3p);
    kE <<<NPIX / 256, 256, 0, stream>>>(d3p, x, y, lam, out);
}

// Round 10
// 120.464 us; speedup vs baseline: 1.4171x; 1.0395x over previous
//
#include <hip/hip_runtime.h>
#include <hip/hip_bf16.h>

// Problem constants
#define BSZ 4
#define CH 64
#define IH 128
#define IW 128
#define PN 63          // number of gaussians
#define TLS 32         // 32x32 outputs per block
#define TLH 36         // extended region for 5x5 halo
#define XSD 40         // staging with halo-of-halo
#define NT 64          // 4 images * 4*4 tiles
#define CG 4           // channels per group
#define NG 16          // channel groups
#define NPOS 324       // 18*18 2x2-position blocks over 36x36
#define NPIX (BSZ*IH*IW)   // 65536
// Spline table: quadratic per-interval fit of act(v) on [-355,355], h=5
#define TBN 142
#define TBH 5.0f
#define TBLO (-355.0f)

// ---------------------------------------------------------------------------
// kT: build per-channel quadratic spline tables of the gaussian-mixture
// activation. Channel 0..63 = w0 rows; channel 64 = w1.
// ---------------------------------------------------------------------------
__global__ __launch_bounds__(160) void kT(const float* __restrict__ w0,
                                          const float* __restrict__ w1,
                                          float4* __restrict__ tab) {
    __shared__ float wsh[PN];
    const int ch = blockIdx.x;
    const float* w = (ch < CH) ? (w0 + (size_t)ch * PN) : w1;
    if (threadIdx.x < PN) wsh[threadIdx.x] = w[threadIdx.x];
    __syncthreads();
    const int i = threadIdx.x;
    if (i >= TBN) return;
    const float x0 = TBLO + TBH * i, xm = x0 + 0.5f * TBH, x1 = x0 + TBH;
    float f0 = 0.f, fm = 0.f, f1 = 0.f;
    for (int p = 0; p < PN; ++p) {
        const float mu = -310.0f + 10.0f * (float)p, wv = wsh[p];
        const float d0 = x0 - mu, dm = xm - mu, d1 = x1 - mu;
        f0 = __fmaf_rn(wv, __expf(d0 * d0 * -0.005f), f0);
        fm = __fmaf_rn(wv, __expf(dm * dm * -0.005f), fm);
        f1 = __fmaf_rn(wv, __expf(d1 * d1 * -0.005f), f1);
    }
    tab[(size_t)ch * TBN + i] =
        make_float4(f0, -3.f * f0 + 4.f * fm - f1, 2.f * f0 - 4.f * fm + 2.f * f1, 0.f);
}

// batched x4 value+gradient from spline: compute 4 indices, issue 4
// independent b128 gathers, then 4 polynomial evals (latency overlap).
__device__ __forceinline__ void act_tab4(const float* __restrict__ v,
                                         const float4* __restrict__ tb,
                                         float* __restrict__ av,
                                         float* __restrict__ ag) {
    float t[4];
    int idx[4];
#pragma unroll
    for (int k = 0; k < 4; ++k) {
        float u = __fmaf_rn(v[k], 1.0f / TBH, -TBLO / TBH);
        u = fminf(fmaxf(u, 0.0f), (float)TBN);
        idx[k] = min((int)u, TBN - 1);
        t[k] = u - (float)idx[k];
    }
    float4 c[4];
#pragma unroll
    for (int k = 0; k < 4; ++k) c[k] = tb[idx[k]];
#pragma unroll
    for (int k = 0; k < 4; ++k) {
        av[k] = __fmaf_rn(t[k], __fmaf_rn(t[k], c[k].z, c[k].y), c[k].x);
        ag[k] = __fmaf_rn(t[k] + t[k], c[k].z, c[k].y) * (1.0f / TBH);
    }
}

__device__ __forceinline__ float act_tab_v(float v, const float4* __restrict__ tb) {
    float u = __fmaf_rn(v, 1.0f / TBH, -TBLO / TBH);
    u = fminf(fmaxf(u, 0.0f), (float)TBN);
    const int idx = min((int)u, TBN - 1);
    const float t = u - (float)idx;
    const float4 c = tb[idx];
    return __fmaf_rn(t, __fmaf_rn(t, c.z, c.y), c.x);
}

// ---------------------------------------------------------------------------
// kAB: per block (tile, 4-channel group):
//   phase 1: conv0+act at ALL ext 36x36 positions, 2x2 register tiles,
//            compile-time register indices only; act gathers batched x4.
//   phase 1.5: rep_pad fixup IN LDS for border tiles.
//   phase 2: partial c1 = sum_cc f1_cc (*) a0_cc -> c1p plane.
//   g0 (bf16) written for the true 32x32 interior only, as bf16x2 pairs.
// ---------------------------------------------------------------------------
__global__ __launch_bounds__(256) void kAB(const float* __restrict__ x,
                                           const float* __restrict__ f0,
                                           const float* __restrict__ b0,
                                           const float* __restrict__ f1,
                                           const float4* __restrict__ tab,
                                           float* __restrict__ c1p,
                                           __hip_bfloat16* __restrict__ g0out) {
    __shared__ float xs[XSD * XSD];          // 6.4 KB
    __shared__ float a0s[CG][TLH * TLH];     // 20.7 KB
    __shared__ float4 tbs[CG][TBN];          // 9.1 KB

    const int tile = blockIdx.x;
    const int cgi  = blockIdx.y;
    const int cg   = cgi * CG;
    const int b    = tile >> 4;
    const int t    = tile & 15;
    const int h0   = (t >> 2) * TLS;
    const int w0p  = (t & 3) * TLS;
    const int tid  = threadIdx.x;

    for (int i = tid; i < XSD * XSD; i += 256) {
        int iy = i / XSD, ix = i - iy * XSD;
        int gy = min(max(h0 + iy - 4, 0), IH - 1);
        int gx = min(max(w0p + ix - 4, 0), IW - 1);
        xs[i] = x[((size_t)b * IH + gy) * IW + gx] * 255.0f;
    }
    for (int i = tid; i < CG * TBN; i += 256) {
        int cc = i / TBN, k = i - cc * TBN;
        tbs[cc][k] = tab[(size_t)(cg + cc) * TBN + k];
    }
    __syncthreads();

    // phase 1: conv0 + act on 2x2 position blocks
    for (int p = tid; p < NPOS; p += 256) {
        const int pyb = p / 18, pxb = p - pyb * 18;
        const int py = 2 * pyb, px = 2 * pxb;
        float win[6][6];
#pragma unroll
        for (int r = 0; r < 6; ++r) {
            const float2* rp = (const float2*)&xs[(py + r) * XSD + px];
            float2 p0 = rp[0], p1 = rp[1], p2 = rp[2];
            win[r][0] = p0.x; win[r][1] = p0.y; win[r][2] = p1.x;
            win[r][3] = p1.y; win[r][4] = p2.x; win[r][5] = p2.y;
        }
        const bool vint = (py >= 2) && (py < 34) && (px >= 2) && (px < 34);
        const int gy0 = h0 + py - 2, gx0 = w0p + px - 2;

#pragma unroll
        for (int cc = 0; cc < CG; ++cc) {
            const int c = cg + cc;
            const float bias = b0[c];
            float acc[4] = {bias, bias, bias, bias};
#pragma unroll
            for (int u = 0; u < 5; ++u)
#pragma unroll
                for (int v = 0; v < 5; ++v) {
                    const float kv = f0[(size_t)c * 25 + u * 5 + v];
                    acc[0] = __fmaf_rn(win[u][v],         kv, acc[0]);
                    acc[1] = __fmaf_rn(win[u][v + 1],     kv, acc[1]);
                    acc[2] = __fmaf_rn(win[u + 1][v],     kv, acc[2]);
                    acc[3] = __fmaf_rn(win[u + 1][v + 1], kv, acc[3]);
                }
            float av[4], ag[4];
            act_tab4(acc, tbs[cc], av, ag);
            *(float2*)&a0s[cc][py * TLH + px]       = make_float2(av[0], av[1]);
            *(float2*)&a0s[cc][(py + 1) * TLH + px] = make_float2(av[2], av[3]);
            if (vint) {
                const size_t gb = ((size_t)b * CH + c) * (IH * IW);
                __hip_bfloat162 r0 = {__float2bfloat16(ag[0]), __float2bfloat16(ag[1])};
                __hip_bfloat162 r1 = {__float2bfloat16(ag[2]), __float2bfloat16(ag[3])};
                *(__hip_bfloat162*)&g0out[gb + (size_t)gy0 * IW + gx0]       = r0;
                *(__hip_bfloat162*)&g0out[gb + (size_t)(gy0 + 1) * IW + gx0] = r1;
            }
        }
    }
    __syncthreads();

    // phase 1.5: rep_pad fixup for outside-image ext positions (border tiles)
    if (h0 == 0 || h0 == IH - TLS || w0p == 0 || w0p == IW - TLS) {
        for (int p = tid; p < TLH * TLH; p += 256) {
            const int py = p / TLH, px = p - py * TLH;
            const int gy = h0 + py - 2, gx = w0p + px - 2;
            if ((unsigned)gy >= IH || (unsigned)gx >= IW) {
                const int cpy = min(max(gy, 0), IH - 1) - h0 + 2;
                const int cpx = min(max(gx, 0), IW - 1) - w0p + 2;
                const int src = cpy * TLH + cpx;
#pragma unroll
                for (int cc = 0; cc < CG; ++cc)
                    a0s[cc][p] = a0s[cc][src];
            }
        }
    }
    __syncthreads();

    // phase 2: partial c1, 2x2/thread -> c1p plane
    const int lx = tid & 15, ly = tid >> 4;
    const int r0 = 2 * ly, c0 = 2 * lx;
    float a00 = 0.f, a01 = 0.f, a10 = 0.f, a11 = 0.f;

#pragma unroll
    for (int cc = 0; cc < CG; ++cc) {
        float win[6][6];
#pragma unroll
        for (int r = 0; r < 6; ++r) {
            const float2* rp = (const float2*)&a0s[cc][(r0 + r) * TLH + c0];
            float2 p0 = rp[0], p1 = rp[1], p2 = rp[2];
            win[r][0] = p0.x; win[r][1] = p0.y; win[r][2] = p1.x;
            win[r][3] = p1.y; win[r][4] = p2.x; win[r][5] = p2.y;
        }
#pragma unroll
        for (int u = 0; u < 5; ++u)
#pragma unroll
            for (int v = 0; v < 5; ++v) {
                const float kv = f1[(size_t)(cg + cc) * 25 + u * 5 + v];
                a00 = __fmaf_rn(win[u][v],         kv, a00);
                a01 = __fmaf_rn(win[u][v + 1],     kv, a01);
                a10 = __fmaf_rn(win[u + 1][v],     kv, a10);
                a11 = __fmaf_rn(win[u + 1][v + 1], kv, a11);
            }
    }

    const size_t base = (size_t)cgi * NPIX + ((size_t)b * IH + h0 + r0) * IW + w0p + c0;
    *(float2*)&c1p[base]      = make_float2(a00, a01);
    *(float2*)&c1p[base + IW] = make_float2(a10, a11);
}

// ---------------------------------------------------------------------------
// kB2: a1 = act_spline(b1 + sum of 16 c1p partials)  (channel-64 table)
// ---------------------------------------------------------------------------
__global__ __launch_bounds__(256) void kB2(const float* __restrict__ c1p,
                                           const float* __restrict__ b1,
                                           const float4* __restrict__ tab,
                                           float* __restrict__ a1) {
    __shared__ float4 tbs[TBN];
    const int tid = threadIdx.x;
    if (tid < TBN) tbs[tid] = tab[(size_t)CH * TBN + tid];
    __syncthreads();

    const int pid = blockIdx.x * 256 + tid;
    float vv = b1[0];
#pragma unroll
    for (int g = 0; g < NG; ++g) vv += c1p[(size_t)g * NPIX + pid];
    a1[pid] = act_tab_v(vv, tbs);
}

// ---------------------------------------------------------------------------
// kCD: per block (tile, 4-channel group):
//   phase 1: dbuf_cc = conv_t5(a1) * g0 on ext 36x36 via 2x2 register tiles;
//            all 8 g0 bf16x2 loads hoisted ABOVE the conv FMAs so L2 latency
//            overlaps 400 FMAs. Validity is uniform per 2x2 block (even
//            coords: both rows/cols of the pair share in-bounds status).
//   phase 2: partial d3 = sum_cc f0_cc full-corr dbuf_cc -> d3p plane.
// ---------------------------------------------------------------------------
__global__ __launch_bounds__(256) void kCD(const float* __restrict__ a1,
                                           const float* __restrict__ f1,
                                           const float* __restrict__ f0,
                                           const __hip_bfloat16* __restrict__ g0,
                                           float* __restrict__ d3p) {
    __shared__ float a1s[XSD * XSD];         // 6.4 KB
    __shared__ float dbs[CG][TLH * TLH];     // 20.7 KB

    const int tile = blockIdx.x;
    const int cgi  = blockIdx.y;
    const int cg   = cgi * CG;
    const int b    = tile >> 4;
    const int t    = tile & 15;
    const int h0   = (t >> 2) * TLS;
    const int w0p  = (t & 3) * TLS;
    const int tid  = threadIdx.x;

    for (int p = tid; p < XSD * XSD; p += 256) {
        int iy = p / XSD, ix = p - iy * XSD;
        int gy = h0 + iy - 4, gx = w0p + ix - 4;
        float v = 0.0f;
        if ((unsigned)gy < IH && (unsigned)gx < IW)
            v = a1[((size_t)b * IH + gy) * IW + gx];
        a1s[p] = v;
    }
    __syncthreads();

    // phase 1: conv_t * g0 on 2x2 position blocks
    for (int p = tid; p < NPOS; p += 256) {
        const int pyb = p / 18, pxb = p - pyb * 18;
        const int py = 2 * pyb, px = 2 * pxb;
        const int gy0 = h0 + py - 2, gx0 = w0p + px - 2;
        // even coords: the 2x2 pair shares validity in each axis
        const bool inb = ((unsigned)gy0 < IH) && ((unsigned)gx0 < IW);

        // hoisted g0 loads: 8 independent bf16x2 (2 rows x 4 channels)
        __hip_bfloat162 gr0[CG], gr1[CG];
#pragma unroll
        for (int cc = 0; cc < CG; ++cc) {
            __hip_bfloat162 z; z.x = __float2bfloat16(0.f); z.y = z.x;
            gr0[cc] = z; gr1[cc] = z;
            if (inb) {
                const size_t gb = ((size_t)b * CH + cg + cc) * (IH * IW);
                gr0[cc] = *(const __hip_bfloat162*)&g0[gb + (size_t)gy0 * IW + gx0];
                gr1[cc] = *(const __hip_bfloat162*)&g0[gb + (size_t)(gy0 + 1) * IW + gx0];
            }
        }

        float win[6][6];
#pragma unroll
        for (int r = 0; r < 6; ++r) {
            const float2* rp = (const float2*)&a1s[(py + r) * XSD + px];
            float2 p0 = rp[0], p1 = rp[1], p2 = rp[2];
            win[r][0] = p0.x; win[r][1] = p0.y; win[r][2] = p1.x;
            win[r][3] = p1.y; win[r][4] = p2.x; win[r][5] = p2.y;
        }

#pragma unroll
        for (int cc = 0; cc < CG; ++cc) {
            const int c = cg + cc;
            float d00 = 0.f, d01 = 0.f, d10 = 0.f, d11 = 0.f;
#pragma unroll
            for (int u = 0; u < 5; ++u)
#pragma unroll
                for (int v = 0; v < 5; ++v) {
                    const float kv = f1[(size_t)c * 25 + u * 5 + v];
                    d00 = __fmaf_rn(win[4 - u][4 - v], kv, d00);
                    d01 = __fmaf_rn(win[4 - u][5 - v], kv, d01);
                    d10 = __fmaf_rn(win[5 - u][4 - v], kv, d10);
                    d11 = __fmaf_rn(win[5 - u][5 - v], kv, d11);
                }
            const float o00 = d00 * __bfloat162float(gr0[cc].x);
            const float o01 = d01 * __bfloat162float(gr0[cc].y);
            const float o10 = d10 * __bfloat162float(gr1[cc].x);
            const float o11 = d11 * __bfloat162float(gr1[cc].y);
            *(float2*)&dbs[cc][py * TLH + px]       = make_float2(o00, o01);
            *(float2*)&dbs[cc][(py + 1) * TLH + px] = make_float2(o10, o11);
        }
    }
    __syncthreads();

    // phase 2: partial d3, 2x2/thread -> d3p plane
    const int lx = tid & 15, ly = tid >> 4;
    const int r0 = 2 * ly, c0 = 2 * lx;
    float a00 = 0.f, a01 = 0.f, a10 = 0.f, a11 = 0.f;

#pragma unroll
    for (int cc = 0; cc < CG; ++cc) {
        float win[6][6];
#pragma unroll
        for (int r = 0; r < 6; ++r) {
            const float2* rp = (const float2*)&dbs[cc][(r0 + r) * TLH + c0];
            float2 p0 = rp[0], p1 = rp[1], p2 = rp[2];
            win[r][0] = p0.x; win[r][1] = p0.y; win[r][2] = p1.x;
            win[r][3] = p1.y; win[r][4] = p2.x; win[r][5] = p2.y;
        }
#pragma unroll
        for (int u = 0; u < 5; ++u)
#pragma unroll
            for (int v = 0; v < 5; ++v) {
                const float kv = f0[(size_t)(cg + cc) * 25 + u * 5 + v];
                a00 = __fmaf_rn(win[4 - u][4 - v], kv, a00);
                a01 = __fmaf_rn(win[4 - u][5 - v], kv, a01);
                a10 = __fmaf_rn(win[5 - u][4 - v], kv, a10);
                a11 = __fmaf_rn(win[5 - u][5 - v], kv, a11);
            }
    }

    const size_t base = (size_t)cgi * NPIX + ((size_t)b * IH + h0 + r0) * IW + w0p + c0;
    *(float2*)&d3p[base]      = make_float2(a00, a01);
    *(float2*)&d3p[base + IW] = make_float2(a10, a11);
}

// ---------------------------------------------------------------------------
// kE: out = x - (sum of 16 d3 partials)/255 - exp(lam)*(x-y)
// ---------------------------------------------------------------------------
__global__ __launch_bounds__(256) void kE(const float* __restrict__ d3p,
                                          const float* __restrict__ x,
                                          const float* __restrict__ y,
                                          const float* __restrict__ lam_param,
                                          float* __restrict__ out) {
    const int pid = blockIdx.x * 256 + threadIdx.x;
    float d3 = 0.0f;
#pragma unroll
    for (int g = 0; g < NG; ++g) d3 += d3p[(size_t)g * NPIX + pid];
    const float elam = __expf(lam_param[0]);
    const float xv = x[pid], yv = y[pid];
    out[pid] = xv - d3 * (1.0f / 255.0f) - elam * (xv - yv);
}

// ---------------------------------------------------------------------------
extern "C" void kernel_launch(void* const* d_in, const int* in_sizes, int n_in,
                              void* d_out, int out_size, void* d_ws, size_t ws_size,
                              hipStream_t stream) {
    const float* x   = (const float*)d_in[0];
    const float* y   = (const float*)d_in[1];
    // d_in[2] = lam (ignored by reference)
    const float* f0  = (const float*)d_in[3];
    const float* b0  = (const float*)d_in[4];
    const float* f1  = (const float*)d_in[5];
    const float* b1  = (const float*)d_in[6];
    const float* w0  = (const float*)d_in[7];
    const float* w1  = (const float*)d_in[8];
    const float* lam = (const float*)d_in[9];
    float* out = (float*)d_out;

    const size_t nch = (size_t)BSZ * CH * IH * IW;   // 4.19M elements
    __hip_bfloat16* g0 = (__hip_bfloat16*)d_ws;      // 8.4 MB (bf16)
    float4* tab = (float4*)(g0 + nch);               // 65*TBN float4 (148 KB)
    float* c1p  = (float*)(tab + (size_t)(CH + 1) * TBN);  // NG*NPIX (4.2 MB)
    float* a1   = c1p + (size_t)NG * NPIX;           // 0.26 MB
    float* d3p  = a1 + NPIX;                         // NG*NPIX (4.2 MB)

    kT <<<CH + 1, 160, 0, stream>>>(w0, w1, tab);
    kAB<<<dim3(NT, NG), 256, 0, stream>>>(x, f0, b0, f1, tab, c1p, g0);
    kB2<<<NPIX / 256, 256, 0, stream>>>(c1p, b1, tab, a1);
    kCD<<<dim3(NT, NG), 256, 0, stream>>>(a1, f1, f0, g0, d3p);
    kE <<<NPIX / 256, 256, 0, stream>>>(d3p, x, y, lam, out);
}